// Round 8
// baseline (88.247 us; speedup 1.0000x reference)
//
#include <hip/hip_runtime.h>

constexpr int N    = 128;
constexpr int C    = 2048;
constexpr int KP   = 4;
constexpr int KN   = 508;
constexpr int K    = 512;     // KP + KN
constexpr int NK   = N * K;   // 65536 gathers
constexpr int NC   = 50000;   // memory bank rows
constexpr int MAXD = 16;      // slots per idx (P(overflow) ~ 1e-8, handled anyway)
constexpr int OCAP = 512;     // overflow list capacity

// ws layout (ints):
//   hdr:  count[NC] | ocount | wcount            <- one hipMemsetAsync(0) covers all
//   rest: pairs[NC*MAXD] | work[NC] | overflow[OCAP] | row_loss(f32)[N]
constexpr int HDR_INTS = NC + 2;

__device__ __forceinline__ int gather_idx(const int* pos_idx, const int* neg_idx, int n, int k) {
    return (k < KP) ? pos_idx[n * KP + k] : neg_idx[n * KN + (k - KP)];
}

// Append each (n,k) to its idx slot list; first claimer also appends idx to
// the compact worklist so the main kernel has zero dead waves.
__global__ __launch_bounds__(256) void build_kernel(
    const int* __restrict__ pos_idx, const int* __restrict__ neg_idx,
    int* __restrict__ count, int* __restrict__ ocount, int* __restrict__ wcount,
    int* __restrict__ pairs, int* __restrict__ work, int* __restrict__ overflow)
{
    const int t = blockIdx.x * 256 + threadIdx.x;   // < NK
    const int n = t >> 9, k = t & (K - 1);
    const int idx = gather_idx(pos_idx, neg_idx, n, k);
    const int packed = (n << 9) | k;
    const int p = atomicAdd(&count[idx], 1);
    if (p < MAXD) {
        pairs[idx * MAXD + p] = packed;
    } else {
        const int o = atomicAdd(ocount, 1);
        if (o < OCAP) overflow[o] = (idx << 16) | packed;
    }
    if (p == 0) {
        const int w = atomicAdd(wcount, 1);
        work[w] = idx;
    }
}

// One wave per REFERENCED M row (via worklist): load the 8 KB row into
// registers once, serve all (n,k) pairs referencing it. M HBM traffic =
// unique rows only, structurally.
__global__ __launch_bounds__(256) void gemv_dedup_kernel(
    const float* __restrict__ inputs,
    const float* __restrict__ M,
    const int*   __restrict__ count,
    const int*   __restrict__ pairs,
    const int*   __restrict__ work,
    const int*   __restrict__ wcount,
    const int*   __restrict__ ocount,
    const int*   __restrict__ overflow,
    float*       __restrict__ logits)
{
    const int wave = threadIdx.x >> 6;
    const int lane = threadIdx.x & 63;
    const int g    = blockIdx.x * 4 + wave;
    if (g >= *wcount) return;            // wcount is L2-hot scalar, cheap exit

    const int idx = work[g];

    // Issue row load + pair-list vector load immediately (independent).
    const float4* __restrict__ b = reinterpret_cast<const float4*>(M + (size_t)idx * C);
    float4 mrow[8];
    #pragma unroll
    for (int i = 0; i < 8; ++i) mrow[i] = b[i * 64 + lane];   // 8 KB/wave, coalesced

    const int4* __restrict__ pl = reinterpret_cast<const int4*>(&pairs[idx * MAXD]);
    int4 p0 = pl[0];                      // first 4 pairs prefetched
    const int cnt = count[idx];           // >=1 by construction

    const float4* __restrict__ A = reinterpret_cast<const float4*>(inputs);

    auto dot_and_store = [&](int packed) {
        const int n = packed >> 9, k = packed & (K - 1);
        const float4* __restrict__ a = A + (size_t)n * (C / 4);
        float acc0 = 0.f, acc1 = 0.f;     // dual accumulators: break FMA chain
        #pragma unroll
        for (int i = 0; i < 8; i += 2) {
            float4 av0 = a[i * 64 + lane];
            float4 av1 = a[(i + 1) * 64 + lane];
            float4 bv0 = mrow[i];
            float4 bv1 = mrow[i + 1];
            acc0 = fmaf(av0.x, bv0.x, acc0); acc1 = fmaf(av1.x, bv1.x, acc1);
            acc0 = fmaf(av0.y, bv0.y, acc0); acc1 = fmaf(av1.y, bv1.y, acc1);
            acc0 = fmaf(av0.z, bv0.z, acc0); acc1 = fmaf(av1.z, bv1.z, acc1);
            acc0 = fmaf(av0.w, bv0.w, acc0); acc1 = fmaf(av1.w, bv1.w, acc1);
        }
        float acc = acc0 + acc1;
        #pragma unroll
        for (int off = 32; off > 0; off >>= 1)
            acc += __shfl_down(acc, off, 64);
        if (lane == 0) logits[n * K + k] = acc;
    };

    const int lim = cnt < MAXD ? cnt : MAXD;
    // first up-to-4 from the prefetched vector
    if (lim > 0) dot_and_store(p0.x);
    if (lim > 1) dot_and_store(p0.y);
    if (lim > 2) dot_and_store(p0.z);
    if (lim > 3) dot_and_store(p0.w);
    for (int j = 4; j < lim; ++j)
        dot_and_store(pairs[idx * MAXD + j]);

    if (cnt > MAXD) {   // ~never
        const int oc = min(*ocount, OCAP);
        for (int i = 0; i < oc; ++i) {
            const int e = overflow[i];
            if ((e >> 16) == idx) dot_and_store(e & 0xFFFF);
        }
    }
}

__global__ __launch_bounds__(512) void softmax_loss_kernel(
    const float* __restrict__ logits,
    const float* __restrict__ cof,
    float*       __restrict__ row_loss)
{
    __shared__ float red[8];
    __shared__ float xs[KP];
    const int n    = blockIdx.x;
    const int t    = threadIdx.x;
    const int wid  = t >> 6;
    const int lane = t & 63;

    float x = logits[n * K + t];

    float m = x;
    #pragma unroll
    for (int off = 1; off < 64; off <<= 1)
        m = fmaxf(m, __shfl_xor(m, off, 64));
    if (lane == 0) red[wid] = m;
    __syncthreads();
    float bm = red[0];
    #pragma unroll
    for (int i = 1; i < 8; ++i) bm = fmaxf(bm, red[i]);

    float s = expf(x - bm);
    #pragma unroll
    for (int off = 1; off < 64; off <<= 1)
        s += __shfl_xor(s, off, 64);
    __syncthreads();
    if (lane == 0) red[wid] = s;
    if (t < KP) xs[t] = x;
    __syncthreads();

    if (t == 0) {
        float bs = 0.f;
        #pragma unroll
        for (int i = 0; i < 8; ++i) bs += red[i];
        const float logZ = bm + logf(bs);
        float acc = 0.f;
        #pragma unroll
        for (int j = 0; j < KP; ++j)
            acc += cof[j] * (xs[j] - logZ);
        row_loss[n] = acc;
    }
}

__global__ __launch_bounds__(128) void loss_reduce_kernel(
    const float* __restrict__ row_loss,
    float*       __restrict__ out)
{
    const int t = threadIdx.x;
    float v = row_loss[t];
    #pragma unroll
    for (int off = 1; off < 64; off <<= 1)
        v += __shfl_xor(v, off, 64);
    __shared__ float red[2];
    if ((t & 63) == 0) red[t >> 6] = v;
    __syncthreads();
    if (t == 0) out[0] = -(red[0] + red[1]) / (float)N;
}

// Fallback (round-2 structure) if ws is too small.
__global__ __launch_bounds__(256) void logits_kernel(
    const float* __restrict__ inputs,
    const int*   __restrict__ pos_idx,
    const int*   __restrict__ neg_idx,
    const float* __restrict__ M,
    float*       __restrict__ logits)
{
    const int wave = threadIdx.x >> 6;
    const int lane = threadIdx.x & 63;
    const int n    = blockIdx.y;
    const int k    = (blockIdx.x << 2) + wave;

    const int idx = (k < KP) ? pos_idx[n * KP + k]
                             : neg_idx[n * KN + (k - KP)];

    const float4* __restrict__ a = reinterpret_cast<const float4*>(inputs + (size_t)n * C);
    const float4* __restrict__ b = reinterpret_cast<const float4*>(M + (size_t)idx * C);

    float acc = 0.f;
    #pragma unroll
    for (int i = 0; i < C / (4 * 64); ++i) {
        float4 av = a[i * 64 + lane];
        float4 bv = b[i * 64 + lane];
        acc = fmaf(av.x, bv.x, acc);
        acc = fmaf(av.y, bv.y, acc);
        acc = fmaf(av.z, bv.z, acc);
        acc = fmaf(av.w, bv.w, acc);
    }
    #pragma unroll
    for (int off = 32; off > 0; off >>= 1)
        acc += __shfl_down(acc, off, 64);
    if (lane == 0) logits[n * K + k] = acc;
}

extern "C" void kernel_launch(void* const* d_in, const int* in_sizes, int n_in,
                              void* d_out, int out_size, void* d_ws, size_t ws_size,
                              hipStream_t stream) {
    const float* inputs  = (const float*)d_in[0];
    const int*   pos_idx = (const int*)d_in[1];
    const int*   neg_idx = (const int*)d_in[2];
    const float* cof     = (const float*)d_in[3];
    const float* M       = (const float*)d_in[4];

    float* out    = (float*)d_out;
    float* logits = out + 1;            // d_out = [loss(1), logits(128*512)]

    const size_t need = (size_t)(HDR_INTS + (size_t)NC * MAXD + NC + OCAP + N) * 4;
    if (ws_size >= need) {
        int*   count    = (int*)d_ws;
        int*   ocount   = count + NC;
        int*   wcount   = ocount + 1;
        int*   pairs    = count + HDR_INTS;
        int*   work     = pairs + (size_t)NC * MAXD;
        int*   overflow = work + NC;
        float* row_loss = (float*)(overflow + OCAP);

        hipMemsetAsync(count, 0, (size_t)HDR_INTS * 4, stream);
        build_kernel<<<NK / 256, 256, 0, stream>>>(pos_idx, neg_idx, count, ocount, wcount,
                                                   pairs, work, overflow);
        gemv_dedup_kernel<<<(NC + 3) / 4, 256, 0, stream>>>(inputs, M, count, pairs, work,
                                                            wcount, ocount, overflow, logits);
        softmax_loss_kernel<<<N, K, 0, stream>>>(logits, cof, row_loss);
        loss_reduce_kernel<<<1, N, 0, stream>>>(row_loss, out);
    } else {
        float* row_loss = (float*)d_ws;
        logits_kernel<<<dim3(K / 4, N), 256, 0, stream>>>(inputs, pos_idx, neg_idx, M, logits);
        softmax_loss_kernel<<<N, K, 0, stream>>>(logits, cof, row_loss);
        loss_reduce_kernel<<<1, N, 0, stream>>>(row_loss, out);
    }
}